// Round 3
// baseline (180.539 us; speedup 1.0000x reference)
//
#include <hip/hip_runtime.h>
#include <math.h>

#define BATCH 16384
#define INPUT_DIM 512
#define HIDDEN 1024
#define NROT 32
#define NANG 496   // 32*31/2

typedef _Float16 half8 __attribute__((ext_vector_type(8)));
typedef float    f32x4 __attribute__((ext_vector_type(4)));

// ---------------------------------------------------------------------------
// Split-precision f16 MFMA GEMM (NT): C = epi(A[M,K] @ B[N,K]^T + bias)
// A = Ah + Al (f16 residual split, 2 MFMA passes); B rounded to f16.
// Tile 128x128xBK32, 4 waves (2x2), each wave 64x64 via mfma_f32_16x16x32_f16.
// LDS XOR-swizzled (chunk ^= row&3) -> conflict-free ds_write_b128/ds_read_b128.
// Double-buffered; next-tile global loads issued before barrier (latency hide).
//   EPI=0: relu(acc+bias) -> float C[M][Nout]
//   EPI=1: sincos(acc+bias) -> float2 C[M][Nout], col guarded (< Nout)
// ---------------------------------------------------------------------------
template<int EPI>
__global__ __launch_bounds__(256) void gemm_nt_mfma(
    const float* __restrict__ A, const float* __restrict__ B,
    const float* __restrict__ bias, float* __restrict__ C,
    int M, int N, int K, int Nout)
{
    constexpr int BK = 32;                    // K per stage (f32 elems)
    __shared__ _Float16 sAh[2][128 * BK];     // 8 KB each buf
    __shared__ _Float16 sAl[2][128 * BK];
    __shared__ _Float16 sB [2][128 * BK];     // total 48 KB

    const int tid = threadIdx.x;
    const int m0 = blockIdx.y * 128;
    const int n0 = blockIdx.x * 128;

    // --- staging: thread owns chunk (row=tid>>2, k8=tid&3) and (row+64, k8)
    //     for both A and B; chunk = 8 consecutive f32 along K.
    const int rA  = tid >> 2;                       // 0..63
    const int k8  = tid & 3;
    const int swW = ((k8 ^ (rA & 3)) << 3);         // swizzled f16 offset in row

    float4 rg[4][2];    // [A row rA][A row rA+64][B row rA][B row rA+64]

    auto load_tile = [&](int kt) {
        const size_t koff = (size_t)kt * BK + k8 * 8;
        const float4* p;
        p = (const float4*)(A + (size_t)(m0 + rA) * K + koff);
        rg[0][0] = p[0]; rg[0][1] = p[1];
        p = (const float4*)(A + (size_t)(m0 + rA + 64) * K + koff);
        rg[1][0] = p[0]; rg[1][1] = p[1];
        const float4 z = make_float4(0.f, 0.f, 0.f, 0.f);
        if (EPI == 0 || (n0 + rA) < N) {
            p = (const float4*)(B + (size_t)(n0 + rA) * K + koff);
            rg[2][0] = p[0]; rg[2][1] = p[1];
        } else { rg[2][0] = z; rg[2][1] = z; }
        if (EPI == 0 || (n0 + rA + 64) < N) {
            p = (const float4*)(B + (size_t)(n0 + rA + 64) * K + koff);
            rg[3][0] = p[0]; rg[3][1] = p[1];
        } else { rg[3][0] = z; rg[3][1] = z; }
    };

    auto cvt_write = [&](int buf) {
        #pragma unroll
        for (int h = 0; h < 2; ++h) {
            const int base = (rA + h * 64) * BK + swW;
            half8 hi, lo;
            const float* f = (const float*)&rg[h][0];
            #pragma unroll
            for (int j = 0; j < 8; ++j) {
                _Float16 hv = (_Float16)f[j];
                hi[j] = hv;
                lo[j] = (_Float16)(f[j] - (float)hv);
            }
            *(half8*)&sAh[buf][base] = hi;
            *(half8*)&sAl[buf][base] = lo;
        }
        #pragma unroll
        for (int h = 0; h < 2; ++h) {
            const int base = (rA + h * 64) * BK + swW;
            half8 bv;
            const float* f = (const float*)&rg[2 + h][0];
            #pragma unroll
            for (int j = 0; j < 8; ++j) bv[j] = (_Float16)f[j];
            *(half8*)&sB[buf][base] = bv;
        }
    };

    // --- compute-side fragment addressing
    const int lane = tid & 63;
    const int wid  = tid >> 6;
    const int wr = wid >> 1, wc = wid & 1;          // wave -> 64x64 sub-tile
    const int fr = lane & 15, fq = lane >> 4;
    const int swR   = ((fq ^ (fr & 3)) << 3);
    const int aBase = (wr * 64 + fr) * BK + swR;
    const int bBase = (wc * 64 + fr) * BK + swR;

    f32x4 acc[4][4];
    #pragma unroll
    for (int i = 0; i < 4; ++i)
        #pragma unroll
        for (int j = 0; j < 4; ++j) acc[i][j] = (f32x4)(0.f);

    const int NT = K / BK;
    load_tile(0);
    cvt_write(0);
    int cur = 0;

    for (int kt = 0; kt < NT; ++kt) {
        const bool more = (kt + 1 < NT);
        if (more) load_tile(kt + 1);        // in flight across barrier + MFMA
        __syncthreads();

        half8 ah[4], al[4], bb[4];
        #pragma unroll
        for (int f = 0; f < 4; ++f) {
            ah[f] = *(const half8*)&sAh[cur][aBase + f * 16 * BK];
            al[f] = *(const half8*)&sAl[cur][aBase + f * 16 * BK];
            bb[f] = *(const half8*)&sB [cur][bBase + f * 16 * BK];
        }
        #pragma unroll
        for (int fm = 0; fm < 4; ++fm)
            #pragma unroll
            for (int fn = 0; fn < 4; ++fn) {
                acc[fm][fn] = __builtin_amdgcn_mfma_f32_16x16x32_f16(
                    al[fm], bb[fn], acc[fm][fn], 0, 0, 0);
                acc[fm][fn] = __builtin_amdgcn_mfma_f32_16x16x32_f16(
                    ah[fm], bb[fn], acc[fm][fn], 0, 0, 0);
            }

        if (more) cvt_write(cur ^ 1);       // prev readers of buf^1 done at barrier
        cur ^= 1;
    }

    // --- epilogue: C row = (l>>4)*4+reg, col = l&15 within each 16x16 frag
    if (EPI == 0) {
        #pragma unroll
        for (int fn = 0; fn < 4; ++fn) {
            const int col = n0 + wc * 64 + fn * 16 + fr;
            const float bv = bias[col];
            #pragma unroll
            for (int fm = 0; fm < 4; ++fm) {
                const int row0 = m0 + wr * 64 + fm * 16 + fq * 4;
                #pragma unroll
                for (int r = 0; r < 4; ++r)
                    C[(size_t)(row0 + r) * Nout + col] =
                        fmaxf(acc[fm][fn][r] + bv, 0.f);
            }
        }
    } else {
        #pragma unroll
        for (int fn = 0; fn < 4; ++fn) {
            const int col = n0 + wc * 64 + fn * 16 + fr;
            if (col < Nout) {
                const float bv = bias[col];
                #pragma unroll
                for (int fm = 0; fm < 4; ++fm) {
                    const int row0 = m0 + wr * 64 + fm * 16 + fq * 4;
                    #pragma unroll
                    for (int r = 0; r < 4; ++r) {
                        const float ang = acc[fm][fn][r] + bv;
                        float s, c;
                        __sincosf(ang, &s, &c);
                        *(float2*)(C + ((size_t)(row0 + r) * Nout + col) * 2) =
                            make_float2(c, s);
                    }
                }
            }
        }
    }
}

// ---------------------------------------------------------------------------
// Givens rotation chain: thread = one row of one batch element's R, all 496
// (i,j) pairs compile-time constants -> v[] stays in registers.
// No LDS: (c,s) pairs are uniform across each 32-lane half-wave, so read them
// straight from global as float4 (2 rotations per load) — 32 identical lane
// addresses coalesce to one L1 transaction, and occupancy is VGPR-capped only.
// ---------------------------------------------------------------------------
__global__ __launch_bounds__(256) void rotate_kernel(
    const float4* __restrict__ cs4, float* __restrict__ out)
{
    const int g = blockIdx.x * 256 + threadIdx.x;
    const int b = g >> 5;      // batch element
    const int r = g & 31;      // row of R

    const float4* __restrict__ p = cs4 + (size_t)b * (NANG / 2);

    float v[NROT];
    #pragma unroll
    for (int c = 0; c < NROT; ++c) v[c] = (c == r) ? 1.f : 0.f;

    float4 q;
    int k = 0;
    #pragma unroll
    for (int i = 0; i < NROT - 1; ++i) {
        #pragma unroll
        for (int j = i + 1; j < NROT; ++j) {
            if ((k & 1) == 0) q = p[k >> 1];          // compile-time offset
            const float c = (k & 1) ? q.z : q.x;
            const float s = (k & 1) ? q.w : q.y;
            const float vi = v[i], vj = v[j];
            v[i] = fmaf(c, vi,  s * vj);
            v[j] = fmaf(c, vj, -s * vi);
            ++k;
        }
    }

    float* op = out + ((size_t)b * (NROT * NROT) + (size_t)r * NROT);
    #pragma unroll
    for (int qq = 0; qq < 8; ++qq)
        *(float4*)(op + qq * 4) = make_float4(v[qq*4], v[qq*4+1], v[qq*4+2], v[qq*4+3]);
}

// ---------------------------------------------------------------------------
extern "C" void kernel_launch(void* const* d_in, const int* in_sizes, int n_in,
                              void* d_out, int out_size, void* d_ws, size_t ws_size,
                              hipStream_t stream)
{
    const float* x  = (const float*)d_in[0];   // [16384, 512]
    const float* W1 = (const float*)d_in[1];   // [1024, 512]
    const float* b1 = (const float*)d_in[2];   // [1024]
    const float* W2 = (const float*)d_in[3];   // [496, 1024]
    const float* b2 = (const float*)d_in[4];   // [496]
    float* out = (float*)d_out;                // [16384, 32, 32]

    float* h  = out;              // d_out (64 MB) doubles as h scratch
    float* cs = (float*)d_ws;     // [16384][496] float2 = 65 MB

    // h = relu(x @ W1^T + b1)
    gemm_nt_mfma<0><<<dim3(HIDDEN / 128, BATCH / 128), 256, 0, stream>>>(
        x, W1, b1, h, BATCH, HIDDEN, INPUT_DIM, HIDDEN);

    // cs = (cos,sin)(h @ W2^T + b2)
    gemm_nt_mfma<1><<<dim3((NANG + 127) / 128, BATCH / 128), 256, 0, stream>>>(
        h, W2, b2, cs, BATCH, NANG, HIDDEN, NANG);

    // R = Givens chain applied to identity
    rotate_kernel<<<dim3(BATCH * NROT / 256), 256, 0, stream>>>(
        (const float4*)cs, out);
}

// Round 4
// 174.689 us; speedup vs baseline: 1.0335x; 1.0335x over previous
//
#include <hip/hip_runtime.h>
#include <math.h>

#define BATCH 16384
#define INPUT_DIM 512
#define HIDDEN 1024
#define NROT 32
#define NANG 496   // 32*31/2

typedef _Float16 half8 __attribute__((ext_vector_type(8)));
typedef float    f32x4 __attribute__((ext_vector_type(4)));

// ---------------------------------------------------------------------------
// Split-precision f16 MFMA GEMM (NT): C = epi(A[M,K] @ B[N,K]^T + bias)
// A = Ah + Al (f16 residual split, 2 MFMA passes); B rounded to f16.
// Tile 128x128xBK32, 4 waves (2x2), each wave 64x64 via mfma_f32_16x16x32_f16.
// LDS XOR-swizzled; double-buffered; next-tile loads in flight across barrier.
//   EPI=0: relu(acc+bias) -> float C[M][Nout]
//   EPI=1: sincos(acc+bias) -> float2 C[M][Nout], col guarded (< Nout)
// ---------------------------------------------------------------------------
template<int EPI>
__global__ __launch_bounds__(256) void gemm_nt_mfma(
    const float* __restrict__ A, const float* __restrict__ B,
    const float* __restrict__ bias, float* __restrict__ C,
    int M, int N, int K, int Nout)
{
    constexpr int BK = 32;                    // K per stage (f32 elems)
    __shared__ _Float16 sAh[2][128 * BK];
    __shared__ _Float16 sAl[2][128 * BK];
    __shared__ _Float16 sB [2][128 * BK];     // total 48 KB

    const int tid = threadIdx.x;
    const int m0 = blockIdx.y * 128;
    const int n0 = blockIdx.x * 128;

    const int rA  = tid >> 2;                       // 0..63
    const int k8  = tid & 3;
    const int swW = ((k8 ^ (rA & 3)) << 3);         // swizzled f16 offset in row

    float4 rg[4][2];

    auto load_tile = [&](int kt) {
        const size_t koff = (size_t)kt * BK + k8 * 8;
        const float4* p;
        p = (const float4*)(A + (size_t)(m0 + rA) * K + koff);
        rg[0][0] = p[0]; rg[0][1] = p[1];
        p = (const float4*)(A + (size_t)(m0 + rA + 64) * K + koff);
        rg[1][0] = p[0]; rg[1][1] = p[1];
        const float4 z = make_float4(0.f, 0.f, 0.f, 0.f);
        if (EPI == 0 || (n0 + rA) < N) {
            p = (const float4*)(B + (size_t)(n0 + rA) * K + koff);
            rg[2][0] = p[0]; rg[2][1] = p[1];
        } else { rg[2][0] = z; rg[2][1] = z; }
        if (EPI == 0 || (n0 + rA + 64) < N) {
            p = (const float4*)(B + (size_t)(n0 + rA + 64) * K + koff);
            rg[3][0] = p[0]; rg[3][1] = p[1];
        } else { rg[3][0] = z; rg[3][1] = z; }
    };

    auto cvt_write = [&](int buf) {
        #pragma unroll
        for (int h = 0; h < 2; ++h) {
            const int base = (rA + h * 64) * BK + swW;
            half8 hi, lo;
            const float* f = (const float*)&rg[h][0];
            #pragma unroll
            for (int j = 0; j < 8; ++j) {
                _Float16 hv = (_Float16)f[j];
                hi[j] = hv;
                lo[j] = (_Float16)(f[j] - (float)hv);
            }
            *(half8*)&sAh[buf][base] = hi;
            *(half8*)&sAl[buf][base] = lo;
        }
        #pragma unroll
        for (int h = 0; h < 2; ++h) {
            const int base = (rA + h * 64) * BK + swW;
            half8 bv;
            const float* f = (const float*)&rg[2 + h][0];
            #pragma unroll
            for (int j = 0; j < 8; ++j) bv[j] = (_Float16)f[j];
            *(half8*)&sB[buf][base] = bv;
        }
    };

    const int lane = tid & 63;
    const int wid  = tid >> 6;
    const int wr = wid >> 1, wc = wid & 1;
    const int fr = lane & 15, fq = lane >> 4;
    const int swR   = ((fq ^ (fr & 3)) << 3);
    const int aBase = (wr * 64 + fr) * BK + swR;
    const int bBase = (wc * 64 + fr) * BK + swR;

    f32x4 acc[4][4];
    #pragma unroll
    for (int i = 0; i < 4; ++i)
        #pragma unroll
        for (int j = 0; j < 4; ++j) acc[i][j] = (f32x4)(0.f);

    const int NT = K / BK;
    load_tile(0);
    cvt_write(0);
    int cur = 0;

    for (int kt = 0; kt < NT; ++kt) {
        const bool more = (kt + 1 < NT);
        if (more) load_tile(kt + 1);
        __syncthreads();

        half8 ah[4], al[4], bb[4];
        #pragma unroll
        for (int f = 0; f < 4; ++f) {
            ah[f] = *(const half8*)&sAh[cur][aBase + f * 16 * BK];
            al[f] = *(const half8*)&sAl[cur][aBase + f * 16 * BK];
            bb[f] = *(const half8*)&sB [cur][bBase + f * 16 * BK];
        }
        #pragma unroll
        for (int fm = 0; fm < 4; ++fm)
            #pragma unroll
            for (int fn = 0; fn < 4; ++fn) {
                acc[fm][fn] = __builtin_amdgcn_mfma_f32_16x16x32_f16(
                    al[fm], bb[fn], acc[fm][fn], 0, 0, 0);
                acc[fm][fn] = __builtin_amdgcn_mfma_f32_16x16x32_f16(
                    ah[fm], bb[fn], acc[fm][fn], 0, 0, 0);
            }

        if (more) cvt_write(cur ^ 1);
        cur ^= 1;
    }

    if (EPI == 0) {
        #pragma unroll
        for (int fn = 0; fn < 4; ++fn) {
            const int col = n0 + wc * 64 + fn * 16 + fr;
            const float bv = bias[col];
            #pragma unroll
            for (int fm = 0; fm < 4; ++fm) {
                const int row0 = m0 + wr * 64 + fm * 16 + fq * 4;
                #pragma unroll
                for (int r = 0; r < 4; ++r)
                    C[(size_t)(row0 + r) * Nout + col] =
                        fmaxf(acc[fm][fn][r] + bv, 0.f);
            }
        }
    } else {
        #pragma unroll
        for (int fn = 0; fn < 4; ++fn) {
            const int col = n0 + wc * 64 + fn * 16 + fr;
            if (col < Nout) {
                const float bv = bias[col];
                #pragma unroll
                for (int fm = 0; fm < 4; ++fm) {
                    const int row0 = m0 + wr * 64 + fm * 16 + fq * 4;
                    #pragma unroll
                    for (int r = 0; r < 4; ++r) {
                        const float ang = acc[fm][fn][r] + bv;
                        float s, c;
                        __sincosf(ang, &s, &c);
                        *(float2*)(C + ((size_t)(row0 + r) * Nout + col) * 2) =
                            make_float2(c, s);
                    }
                }
            }
        }
    }
}

// ---------------------------------------------------------------------------
// Givens rotation chain, explicit software pipeline:
//   - 31 chunks x 16 rotations; chunk k+1's 8 float4 loads (compile-time
//     immediate offsets) are issued BEFORE chunk k's 64 FMAs -> loads stay
//     in flight under compute instead of JIT-scheduled per rotation.
//   - (i,j) from constexpr table -> v[] indices all compile-time (registers).
//   - Output staged through XOR-swizzled LDS transpose so global stores are
//     contiguous 1KB/wave-instruction (kills the 1.84x partial-line write
//     amplification seen in rocprof).
// ---------------------------------------------------------------------------
struct IJTbl { unsigned char i[NANG]; unsigned char j[NANG]; };
constexpr IJTbl make_ij_tbl() {
    IJTbl t{};
    int k = 0;
    for (int i = 0; i < NROT - 1; ++i)
        for (int j = i + 1; j < NROT; ++j) { t.i[k] = (unsigned char)i; t.j[k] = (unsigned char)j; ++k; }
    return t;
}
constexpr IJTbl IJT = make_ij_tbl();

__global__ __launch_bounds__(256, 4) void rotate_kernel(
    const float4* __restrict__ cs4, float* __restrict__ out)
{
    __shared__ float lds[8192];   // 32 KB: 256 threads x 32 floats

    const int tid = threadIdx.x;
    const int g = blockIdx.x * 256 + tid;
    const int b = g >> 5;      // batch element
    const int r = g & 31;      // row of R

    const float4* __restrict__ p = cs4 + (size_t)b * (NANG / 2);

    float v[NROT];
    #pragma unroll
    for (int c = 0; c < NROT; ++c) v[c] = (c == r) ? 1.f : 0.f;

    float4 buf[2][8];
    #pragma unroll
    for (int q = 0; q < 8; ++q) buf[0][q] = p[q];

    #pragma unroll
    for (int ch = 0; ch < 31; ++ch) {
        const int cur = ch & 1;
        if (ch + 1 < 31) {
            #pragma unroll
            for (int q = 0; q < 8; ++q)
                buf[cur ^ 1][q] = p[(ch + 1) * 8 + q];   // in flight over compute
        }
        #pragma unroll
        for (int t = 0; t < 16; ++t) {
            const int k = ch * 16 + t;
            const float4 q4 = buf[cur][t >> 1];
            const float c = (t & 1) ? q4.z : q4.x;
            const float s = (t & 1) ? q4.w : q4.y;
            const int i = IJT.i[k], j = IJT.j[k];
            const float vi = v[i], vj = v[j];
            v[i] = fmaf(c, vi,  s * vj);
            v[j] = fmaf(c, vj, -s * vi);
        }
    }

    // ---- coalesced store via swizzled LDS transpose ----
    // write: thread row = 32 floats at lds[tid*32 + swz(q)*4], swz(q)=q^(tid&7)
    #pragma unroll
    for (int q = 0; q < 8; ++q) {
        *(float4*)&lds[tid * 32 + ((q ^ (tid & 7)) << 2)] =
            make_float4(v[q*4], v[q*4+1], v[q*4+2], v[q*4+3]);
    }
    __syncthreads();

    // read linear flat: f4 = s*256 + tid  (float4 units) -> row = f4>>3, q' = f4&7
    float* obase = out + (size_t)blockIdx.x * 8192;
    #pragma unroll
    for (int s = 0; s < 8; ++s) {
        const int f4  = s * 256 + tid;
        const int row = f4 >> 3;
        const int qq  = f4 & 7;
        const float4 val = *(const float4*)&lds[row * 32 + ((qq ^ (row & 7)) << 2)];
        *(float4*)(obase + (size_t)f4 * 4) = val;
    }
}

// ---------------------------------------------------------------------------
extern "C" void kernel_launch(void* const* d_in, const int* in_sizes, int n_in,
                              void* d_out, int out_size, void* d_ws, size_t ws_size,
                              hipStream_t stream)
{
    const float* x  = (const float*)d_in[0];   // [16384, 512]
    const float* W1 = (const float*)d_in[1];   // [1024, 512]
    const float* b1 = (const float*)d_in[2];   // [1024]
    const float* W2 = (const float*)d_in[3];   // [496, 1024]
    const float* b2 = (const float*)d_in[4];   // [496]
    float* out = (float*)d_out;                // [16384, 32, 32]

    float* h  = out;              // d_out (64 MB) doubles as h scratch
    float* cs = (float*)d_ws;     // [16384][496] float2 = 65 MB

    gemm_nt_mfma<0><<<dim3(HIDDEN / 128, BATCH / 128), 256, 0, stream>>>(
        x, W1, b1, h, BATCH, HIDDEN, INPUT_DIM, HIDDEN);

    gemm_nt_mfma<1><<<dim3((NANG + 127) / 128, BATCH / 128), 256, 0, stream>>>(
        h, W2, b2, cs, BATCH, NANG, HIDDEN, NANG);

    rotate_kernel<<<dim3(BATCH * NROT / 256), 256, 0, stream>>>(
        (const float4*)cs, out);
}